// Round 9
// baseline (475.598 us; speedup 1.0000x reference)
//
#include <hip/hip_runtime.h>
#include <math.h>

#define KS    5
#define K2    25
#define BB    4
#define HH    256
#define WW    256
#define PLANE (HH * WW)
#define LROWD 264     // dwords per tile row: [2 halo][256 px][2 halo][4 pad]
#define PTILE 1864    // 7 rows * 264 + 16 pad
#define NTHR  256

typedef __attribute__((ext_vector_type(2))) _Float16 half2_t;
typedef __attribute__((ext_vector_type(4))) float    f32x4;

static __device__ __forceinline__ half2_t u2h(unsigned u) { return __builtin_bit_cast(half2_t, u); }

static __device__ __forceinline__ unsigned pkrtz(float a, float b) {
    auto h = __builtin_amdgcn_cvt_pkrtz(a, b);
    return __builtin_bit_cast(unsigned, h);
}

static __device__ __forceinline__ float dot2(half2_t a, half2_t b, float c) {
#if __has_builtin(__builtin_amdgcn_fdot2)
    return __builtin_amdgcn_fdot2(a, b, c, false);
#else
    return (float)a.x * (float)b.x + ((float)a.y * (float)b.y + c);
#endif
}

// ROUND 9: ABLATION PROBE. 8 rounds of hypothesis-driven edits left per-
// dispatch time pinned at ~41us (component floors: VALU ~16, LDS ~10,
// HBM ~6-11 -> measured ~ SUM). Instead of guessing which term dominates,
// this round launches ablated variants (garbage output, overwritten by the
// final correct launch on the same stream) with REPS=4 so each lands above
// the 42us fill dispatches in the rocprof top-5:
//   <7,4> FULL x4          : in-probe baseline (~164us expected)
//   <6,4> NO-LDS-READ x4   : compute on address-derived constants
//   <5,4> NO-STAGE x4      : no global loads/pkrtz/ds_write/vmcnt (LDS=0s)
//   <3,4> NO-BARRIER x4    : full work, no loop __syncthreads (garbage-safe)
//   <7,1> FULL (LAST)      : the real kernel -- correct output.
// MODE bits: 1=LDS reads, 2=staging, 4=barriers.
template<int MODE, int REPS>
__global__ __launch_bounds__(NTHR, 2)
void local_attn_kernel(const float* __restrict__ x,
                       const float* __restrict__ kern,
                       float* __restrict__ out)
{
    constexpr bool DO_READ  = (MODE & 1) != 0;
    constexpr bool DO_STAGE = (MODE & 2) != 0;
    constexpr bool DO_BAR   = (MODE & 4) != 0;

    __shared__ unsigned ldsu[2 * 4 * PTILE];
    __shared__ float kw[K2];

    const int tid = threadIdx.x;
    for (int i = tid; i < 2 * 4 * PTILE; i += NTHR) ldsu[i] = 0u;
    if (tid < K2) kw[tid] = kern[tid] * (1.0f / KS);

    const int lane = tid & 63;
    const int wv   = tid >> 6;
    const int ty   = wv >> 1;                       // output row in block
    const int cg   = lane >> 5;                     // pair-half (0/1)
    const int tx   = ((wv & 1) << 5) | (lane & 31); // pixel-group 0..63
    const int w0   = tx << 2;

    // XCD swizzle: each XCD owns a contiguous 32-row band (halo L2-shared)
    const int bx     = blockIdx.x;
    const int hgroup = ((bx & 7) << 4) | (bx >> 3);
    const int h0     = hgroup * 2;
    const int h      = h0 + ty;
    const int b      = blockIdx.y;

    const float* xb = x + (size_t)b * 64 * PLANE;

    // 6 staging tasks/thread: task i -> (pair, tile row, 4-px segment)
    int gofs[6], lofs[6], pofs[6];
#pragma unroll
    for (int i = 0; i < 6; ++i) {
        const int rp   = (tid >> 6) + 4 * i;        // 0..23 (wave-uniform)
        const int row  = rp % 6;
        const int pair = rp / 6;
        const int r    = h0 - 2 + row;
        const bool v   = (unsigned)r < (unsigned)HH;
        gofs[i] = min(max(r, 0), HH - 1) * WW + (tid & 63) * 4;
        pofs[i] = pair * 2 * PLANE;
        lofs[i] = pair * PTILE + (v ? row : 6) * LROWD + 2 + (tid & 63) * 4;
    }

    f32x4 pa[6], pb[6];
    auto prefetch = [&](int st) {
        const float* xc = xb + (size_t)((st < 4) ? 32 + st * 8 : (st - 4) * 8) * PLANE;
#pragma unroll
        for (int i = 0; i < 6; ++i) {
            const float* p0 = xc + pofs[i] + gofs[i];
            const float* p1 = p0 + PLANE;
            // volatile asm: unsinkable, pinned at stage top in program order
            asm volatile("global_load_dwordx4 %0, %1, off"
                         : "=v"(pa[i]) : "v"(p0));
            asm volatile("global_load_dwordx4 %0, %1, off"
                         : "=v"(pb[i]) : "v"(p1));
        }
        __builtin_amdgcn_sched_barrier(0);
    };
    auto cvtwrite = [&](int bufi) {
        asm volatile("s_waitcnt vmcnt(0)" ::: "memory");
        __builtin_amdgcn_sched_barrier(0);
        unsigned* lb = ldsu + bufi * 4 * PTILE;
#pragma unroll
        for (int i = 0; i < 6; ++i) {
            const unsigned d0 = pkrtz(pa[i].x, pb[i].x);
            const unsigned d1 = pkrtz(pa[i].y, pb[i].y);
            const unsigned d2 = pkrtz(pa[i].z, pb[i].z);
            const unsigned d3 = pkrtz(pa[i].w, pb[i].w);
            *(uint2*)(lb + lofs[i])     = make_uint2(d0, d1);
            *(uint2*)(lb + lofs[i] + 2) = make_uint2(d2, d3);
        }
    };

    // window read: either real ds_read or address-derived substitute
    auto readwin = [&](const unsigned* rp, uint4& r0, uint4& r1, int salt) {
        if constexpr (DO_READ) {
            r0 = *(const uint4*)(rp);
            r1 = *(const uint4*)(rp + 4);
        } else {
            unsigned sd = ((unsigned)(size_t)rp ^ (unsigned)(salt * 2654435761u));
            sd &= 0x3bff3bffu;   // keep f16 values small/positive
            r0 = make_uint4(sd, sd ^ 0x00010000u, sd ^ 0x00000001u, sd ^ 0x00010001u);
            r1 = make_uint4(sd ^ 0x00020000u, sd ^ 0x00020001u, sd ^ 0x00030000u, sd ^ 0x00030001u);
        }
    };

    float s[4][K2];
#pragma unroll
    for (int p = 0; p < 4; ++p)
#pragma unroll
        for (int k = 0; k < K2; ++k) s[p][k] = 0.0f;

    __syncthreads();          // B0 always: zero-init + kw visible

#pragma unroll 1
    for (int rep = 0; rep < REPS; ++rep) {
        if constexpr (DO_STAGE) {
            prefetch(0);
            cvtwrite(0);
        }
        if constexpr (DO_BAR) __syncthreads();

#pragma unroll 1
        for (int t = 0; t < 8; ++t) {
            if constexpr (DO_STAGE) {
                if (t + 1 < 8) prefetch(t + 1);
            }
            const unsigned* buf = ldsu + (t & 1) * 4 * PTILE;

            if (t < 4) {
                // ---- score: 2 channel-pairs per lane-half, dot2 accumulate ----
#pragma unroll
                for (int dp = 0; dp < 2; ++dp) {
                    const unsigned* tb = buf + (cg * 2 + dp) * PTILE;
                    half2_t ctr[4];
                    {   // center row (i=2) first: f[q] = pair at px w0-2+q
                        uint4 r0, r1;
                        readwin(tb + (ty + 2) * LROWD + w0, r0, r1, t * 8 + dp);
                        half2_t f[8] = {u2h(r0.x), u2h(r0.y), u2h(r0.z), u2h(r0.w),
                                        u2h(r1.x), u2h(r1.y), u2h(r1.z), u2h(r1.w)};
#pragma unroll
                        for (int p = 0; p < 4; ++p) ctr[p] = f[p + 2];
#pragma unroll
                        for (int j = 0; j < KS; ++j)
#pragma unroll
                            for (int p = 0; p < 4; ++p)
                                s[p][2 * KS + j] = dot2(f[p + j], ctr[p], s[p][2 * KS + j]);
                    }
#pragma unroll
                    for (int i = 0; i < KS; ++i) {
                        if (i == 2) continue;
                        uint4 r0, r1;
                        readwin(tb + (ty + i) * LROWD + w0, r0, r1, t * 8 + dp + i);
                        half2_t f[8] = {u2h(r0.x), u2h(r0.y), u2h(r0.z), u2h(r0.w),
                                        u2h(r1.x), u2h(r1.y), u2h(r1.z), u2h(r1.w)};
#pragma unroll
                        for (int j = 0; j < KS; ++j)
#pragma unroll
                            for (int p = 0; p < 4; ++p)
                                s[p][i * KS + j] = dot2(f[p + j], ctr[p], s[p][i * KS + j]);
                    }
                }
                if (t == 3) {
                    // combine pair-halves, then softmax over 25 taps.
#pragma unroll
                    for (int p = 0; p < 4; ++p)
#pragma unroll
                        for (int k = 0; k < K2; ++k)
                            s[p][k] += __shfl_xor(s[p][k], 32, 64);
#pragma unroll
                    for (int p = 0; p < 4; ++p) {
                        float mx = -INFINITY;
#pragma unroll
                        for (int k = 0; k < K2; ++k) {
                            float v = s[p][k] * kw[k];
                            s[p][k] = v;
                            mx = fmaxf(mx, v);
                        }
                        float sum = 0.0f;
#pragma unroll
                        for (int k = 0; k < K2; ++k) {
                            float e = __expf(s[p][k] - mx);
                            s[p][k] = e;
                            sum += e;
                        }
                        const float inv = 1.0f / sum;
#pragma unroll
                        for (int k = 0; k < K2; ++k) s[p][k] *= inv;
                    }
                }
            } else {
                // ---- output: weighted sum; fp32 accumulate via mixed FMA ----
                const int chb = (t - 4) * 8;
#pragma unroll
                for (int dp = 0; dp < 2; ++dp) {
                    const unsigned* tb = buf + (cg * 2 + dp) * PTILE;
                    float alo[4] = {0.f, 0.f, 0.f, 0.f};
                    float ahi[4] = {0.f, 0.f, 0.f, 0.f};
#pragma unroll
                    for (int i = 0; i < KS; ++i) {
                        uint4 r0, r1;
                        readwin(tb + (ty + i) * LROWD + w0, r0, r1, t * 16 + dp + i);
                        half2_t f[8] = {u2h(r0.x), u2h(r0.y), u2h(r0.z), u2h(r0.w),
                                        u2h(r1.x), u2h(r1.y), u2h(r1.z), u2h(r1.w)};
#pragma unroll
                        for (int j = 0; j < KS; ++j)
#pragma unroll
                            for (int p = 0; p < 4; ++p) {
                                const half2_t v = f[p + j];
                                const float  wgt = s[p][i * KS + j];
                                alo[p] = fmaf((float)v.x, wgt, alo[p]);
                                ahi[p] = fmaf((float)v.y, wgt, ahi[p]);
                            }
                    }
                    const int c0 = chb + (cg * 2 + dp) * 2;
                    float* op = out + ((size_t)b * 32 + c0) * PLANE + h * WW + w0;
                    *(float4*)op           = make_float4(alo[0], alo[1], alo[2], alo[3]);
                    *(float4*)(op + PLANE) = make_float4(ahi[0], ahi[1], ahi[2], ahi[3]);
                }
            }

            if (t + 1 < 8) {
                if constexpr (DO_STAGE) cvtwrite((t + 1) & 1);
                if constexpr (DO_BAR) __syncthreads();
            }
        }
        if constexpr (DO_BAR) {
            if (rep + 1 < REPS) __syncthreads();
        }
    }
}

extern "C" void kernel_launch(void* const* d_in, const int* in_sizes, int n_in,
                              void* d_out, int out_size, void* d_ws, size_t ws_size,
                              hipStream_t stream) {
    const float* x    = (const float*)d_in[0];
    const float* kern = (const float*)d_in[1];
    float*       out  = (float*)d_out;

    dim3 grid(HH / 2, BB, 1);
    dim3 block(NTHR, 1, 1);

    // Ablation probes (garbage output, overwritten by the final launch).
    hipLaunchKernelGGL((local_attn_kernel<7, 4>), grid, block, 0, stream, x, kern, out); // FULL x4 baseline
    hipLaunchKernelGGL((local_attn_kernel<6, 4>), grid, block, 0, stream, x, kern, out); // no LDS reads
    hipLaunchKernelGGL((local_attn_kernel<5, 4>), grid, block, 0, stream, x, kern, out); // no staging
    hipLaunchKernelGGL((local_attn_kernel<3, 4>), grid, block, 0, stream, x, kern, out); // no barriers
    // The real kernel: last on the stream -> correct output.
    hipLaunchKernelGGL((local_attn_kernel<7, 1>), grid, block, 0, stream, x, kern, out);
}

// Round 10
// 108.471 us; speedup vs baseline: 4.3846x; 4.3846x over previous
//
#include <hip/hip_runtime.h>
#include <math.h>

#define KS    5
#define K2    25
#define BB    4
#define HH    256
#define WW    256
#define PLANE (HH * WW)
#define LROWD 264     // dwords per tile row: [2 halo][256 px][2 halo][4 pad]
#define PTILE 2376    // 9 rows (8 data + 1 dump) * 264; %32==8 -> pair stride 8 banks, cg stride 16
#define NTHR  512

typedef __attribute__((ext_vector_type(2))) _Float16 half2_t;
typedef __attribute__((ext_vector_type(4))) float    f32x4;

static __device__ __forceinline__ half2_t u2h(unsigned u) { return __builtin_bit_cast(half2_t, u); }

static __device__ __forceinline__ unsigned pkrtz(float a, float b) {
    auto h = __builtin_amdgcn_cvt_pkrtz(a, b);   // __fp16 ext_vector(2), 4 bytes
    return __builtin_bit_cast(unsigned, h);
}

static __device__ __forceinline__ float dot2(half2_t a, half2_t b, float c) {
#if __has_builtin(__builtin_amdgcn_fdot2)
    return __builtin_amdgcn_fdot2(a, b, c, false);
#else
    return (float)a.x * (float)b.x + ((float)a.y * (float)b.y + c);
#endif
}

// ROUND 10: 4-ROW BANDS (amortization harvest from the r9 ablation probe).
// r9 probe readout: FULL x4-rep = 119.6us -> 29.9us/rep vs 41.6us single
// dispatch => ~12-15us per-dispatch overhead (launch ramp/prologue/drain);
// no single component ablation (LDS reads / staging / barriers) saved more
// than ~9us/rep (avg ~3.5) -> no dominant removable phase; the win left on
// the table is amortization + halo efficiency.
// Block = 4 output rows x 256 px, 8 waves (2 waves per row, channel-pair
// split across lane halves -- same per-thread compute as the 107.6us r4
// kernel). Grid 256 blocks (64 bands x 4 batch) = 1 block/CU, 8 waves/CU
// (unchanged). Each band stages 8 input rows for 4 output rows (2x) vs 6
// rows for 2 (3x): staging loads/pkrtz/ds_writes cut 33%. LDS 76.3 KB,
// PTILE 2376 keeps the old bank phasing exactly (pair stride %32==8).
// Keeps r4's volatile-asm pinned prefetch + manual vmcnt(0) drain.
__global__ __launch_bounds__(NTHR, 1)
void local_attn_kernel(const float* __restrict__ x,
                       const float* __restrict__ kern,
                       float* __restrict__ out)
{
    __shared__ unsigned ldsu[2 * 4 * PTILE];
    __shared__ float kw[K2];

    const int tid = threadIdx.x;
    for (int i = tid; i < 2 * 4 * PTILE; i += NTHR) ldsu[i] = 0u;
    if (tid < K2) kw[tid] = kern[tid] * (1.0f / KS);

    const int lane = tid & 63;
    const int wv   = tid >> 6;                      // 0..7
    const int ty   = wv >> 1;                       // output row in block (0..3)
    const int cg   = lane >> 5;                     // pair-half (0/1)
    const int tx   = ((wv & 1) << 5) | (lane & 31); // pixel-group 0..63
    const int w0   = tx << 2;

    // XCD swizzle over 64 bands: each XCD owns a contiguous 8-band region
    const int bx     = blockIdx.x;                  // 0..63
    const int hgroup = ((bx & 7) << 3) | (bx >> 3);
    const int h0     = hgroup * 4;
    const int h      = h0 + ty;
    const int b      = blockIdx.y;

    const float* xb = x + (size_t)b * 64 * PLANE;

    // 4 staging tasks/thread: task i -> (pair, tile row); lane -> 4-px segment
    int gofs[4], lofs[4], pofs[4];
#pragma unroll
    for (int i = 0; i < 4; ++i) {
        const int rp   = wv + 8 * i;                // 0..31 (wave-uniform)
        const int row  = rp & 7;                    // tile row 0..7
        const int pair = rp >> 3;                   // 0..3
        const int r    = h0 - 2 + row;
        const bool v   = (unsigned)r < (unsigned)HH;
        gofs[i] = min(max(r, 0), HH - 1) * WW + lane * 4;
        pofs[i] = pair * 2 * PLANE;
        lofs[i] = pair * PTILE + (v ? row : 8) * LROWD + 2 + lane * 4;  // row 8 = dump
    }

    f32x4 pa[4], pb[4];
    auto prefetch = [&](int st) {
        const float* xc = xb + (size_t)((st < 4) ? 32 + st * 8 : (st - 4) * 8) * PLANE;
#pragma unroll
        for (int i = 0; i < 4; ++i) {
            const float* p0 = xc + pofs[i] + gofs[i];
            const float* p1 = p0 + PLANE;
            // volatile asm: unsinkable, pinned at stage top in program order
            asm volatile("global_load_dwordx4 %0, %1, off"
                         : "=v"(pa[i]) : "v"(p0));
            asm volatile("global_load_dwordx4 %0, %1, off"
                         : "=v"(pb[i]) : "v"(p1));
        }
        __builtin_amdgcn_sched_barrier(0);
    };
    auto cvtwrite = [&](int bufi) {
        // compiler can't track the asm loads' vmcnt -- wait manually, and
        // fence the scheduler so pkrtz/ds_write can't hoist above the wait.
        asm volatile("s_waitcnt vmcnt(0)" ::: "memory");
        __builtin_amdgcn_sched_barrier(0);
        unsigned* lb = ldsu + bufi * 4 * PTILE;
#pragma unroll
        for (int i = 0; i < 4; ++i) {
            const unsigned d0 = pkrtz(pa[i].x, pb[i].x);
            const unsigned d1 = pkrtz(pa[i].y, pb[i].y);
            const unsigned d2 = pkrtz(pa[i].z, pb[i].z);
            const unsigned d3 = pkrtz(pa[i].w, pb[i].w);
            *(uint2*)(lb + lofs[i])     = make_uint2(d0, d1);
            *(uint2*)(lb + lofs[i] + 2) = make_uint2(d2, d3);
        }
    };

    float s[4][K2];
#pragma unroll
    for (int p = 0; p < 4; ++p)
#pragma unroll
        for (int k = 0; k < K2; ++k) s[p][k] = 0.0f;

    __syncthreads();          // zero-init + kw visible
    prefetch(0);
    cvtwrite(0);
    __syncthreads();

#pragma unroll 1
    for (int t = 0; t < 8; ++t) {
        if (t + 1 < 8) prefetch(t + 1);
        const unsigned* buf = ldsu + (t & 1) * 4 * PTILE;

        if (t < 4) {
            // ---- score: 2 channel-pairs per lane-half, dot2 accumulate ----
#pragma unroll
            for (int dp = 0; dp < 2; ++dp) {
                const unsigned* tb = buf + (cg * 2 + dp) * PTILE;
                half2_t ctr[4];
                {   // center row (i=2) first: f[q] = pair at px w0-2+q
                    const unsigned* rp = tb + (ty + 2) * LROWD + w0;
                    const uint4 r0 = *(const uint4*)(rp);
                    const uint4 r1 = *(const uint4*)(rp + 4);
                    half2_t f[8] = {u2h(r0.x), u2h(r0.y), u2h(r0.z), u2h(r0.w),
                                    u2h(r1.x), u2h(r1.y), u2h(r1.z), u2h(r1.w)};
#pragma unroll
                    for (int p = 0; p < 4; ++p) ctr[p] = f[p + 2];
#pragma unroll
                    for (int j = 0; j < KS; ++j)
#pragma unroll
                        for (int p = 0; p < 4; ++p)
                            s[p][2 * KS + j] = dot2(f[p + j], ctr[p], s[p][2 * KS + j]);
                }
#pragma unroll
                for (int i = 0; i < KS; ++i) {
                    if (i == 2) continue;
                    const unsigned* rp = tb + (ty + i) * LROWD + w0;
                    const uint4 r0 = *(const uint4*)(rp);
                    const uint4 r1 = *(const uint4*)(rp + 4);
                    half2_t f[8] = {u2h(r0.x), u2h(r0.y), u2h(r0.z), u2h(r0.w),
                                    u2h(r1.x), u2h(r1.y), u2h(r1.z), u2h(r1.w)};
#pragma unroll
                    for (int j = 0; j < KS; ++j)
#pragma unroll
                        for (int p = 0; p < 4; ++p)
                            s[p][i * KS + j] = dot2(f[p + j], ctr[p], s[p][i * KS + j]);
                }
            }
            if (t == 3) {
                // combine pair-halves, then softmax over 25 taps.
                // zero-padded taps score exactly 0 and keep their denominator
                // share (matches reference).
#pragma unroll
                for (int p = 0; p < 4; ++p)
#pragma unroll
                    for (int k = 0; k < K2; ++k)
                        s[p][k] += __shfl_xor(s[p][k], 32, 64);
#pragma unroll
                for (int p = 0; p < 4; ++p) {
                    float mx = -INFINITY;
#pragma unroll
                    for (int k = 0; k < K2; ++k) {
                        float v = s[p][k] * kw[k];
                        s[p][k] = v;
                        mx = fmaxf(mx, v);
                    }
                    float sum = 0.0f;
#pragma unroll
                    for (int k = 0; k < K2; ++k) {
                        float e = __expf(s[p][k] - mx);
                        s[p][k] = e;
                        sum += e;
                    }
                    const float inv = 1.0f / sum;
#pragma unroll
                    for (int k = 0; k < K2; ++k) s[p][k] *= inv;
                }
            }
        } else {
            // ---- output: weighted sum; fp32 accumulate via mixed FMA ----
            const int chb = (t - 4) * 8;
#pragma unroll
            for (int dp = 0; dp < 2; ++dp) {
                const unsigned* tb = buf + (cg * 2 + dp) * PTILE;
                float alo[4] = {0.f, 0.f, 0.f, 0.f};
                float ahi[4] = {0.f, 0.f, 0.f, 0.f};
#pragma unroll
                for (int i = 0; i < KS; ++i) {
                    const unsigned* rp = tb + (ty + i) * LROWD + w0;
                    const uint4 r0 = *(const uint4*)(rp);
                    const uint4 r1 = *(const uint4*)(rp + 4);
                    half2_t f[8] = {u2h(r0.x), u2h(r0.y), u2h(r0.z), u2h(r0.w),
                                    u2h(r1.x), u2h(r1.y), u2h(r1.z), u2h(r1.w)};
#pragma unroll
                    for (int j = 0; j < KS; ++j)
#pragma unroll
                        for (int p = 0; p < 4; ++p) {
                            const half2_t v = f[p + j];
                            const float  wgt = s[p][i * KS + j];
                            alo[p] = fmaf((float)v.x, wgt, alo[p]);
                            ahi[p] = fmaf((float)v.y, wgt, ahi[p]);
                        }
                }
                const int c0 = chb + (cg * 2 + dp) * 2;
                float* op = out + ((size_t)b * 32 + c0) * PLANE + h * WW + w0;
                *(float4*)op           = make_float4(alo[0], alo[1], alo[2], alo[3]);
                *(float4*)(op + PLANE) = make_float4(ahi[0], ahi[1], ahi[2], ahi[3]);
            }
        }

        if (t + 1 < 8) {
            cvtwrite((t + 1) & 1);
            __syncthreads();
        }
    }
}

extern "C" void kernel_launch(void* const* d_in, const int* in_sizes, int n_in,
                              void* d_out, int out_size, void* d_ws, size_t ws_size,
                              hipStream_t stream) {
    const float* x    = (const float*)d_in[0];
    const float* kern = (const float*)d_in[1];
    float*       out  = (float*)d_out;

    dim3 grid(HH / 4, BB, 1);     // 64 four-row bands x 4 batch = 256 blocks
    dim3 block(NTHR, 1, 1);
    hipLaunchKernelGGL(local_attn_kernel, grid, block, 0, stream, x, kern, out);
}

// Round 12
// 107.683 us; speedup vs baseline: 4.4167x; 1.0073x over previous
//
#include <hip/hip_runtime.h>
#include <math.h>

#define KS    5
#define K2    25
#define BB    4
#define HH    256
#define WW    256
#define PLANE (HH * WW)
#define LROWD 264     // dwords per tile row: [2 halo][256 px][2 halo][4 pad]
#define PTILE 1864    // 7 rows * 264 + 16 pad; %32==8 -> cg stride (2*PTILE) == 16 banks
#define NTHR  256

typedef __attribute__((ext_vector_type(2))) _Float16 half2_t;
typedef __attribute__((ext_vector_type(4))) float    f32x4;

static __device__ __forceinline__ half2_t u2h(unsigned u) { return __builtin_bit_cast(half2_t, u); }

static __device__ __forceinline__ unsigned pkrtz(float a, float b) {
    auto h = __builtin_amdgcn_cvt_pkrtz(a, b);   // __fp16 ext_vector(2), 4 bytes
    return __builtin_bit_cast(unsigned, h);
}

static __device__ __forceinline__ float dot2(half2_t a, half2_t b, float c) {
#if __has_builtin(__builtin_amdgcn_fdot2)
    return __builtin_amdgcn_fdot2(a, b, c, false);
#else
    return (float)a.x * (float)b.x + ((float)a.y * (float)b.y + c);
#endif
}

// Block = 2 output rows x 256 cols, 4 waves, 4 px/thread, channel-pair f16 tile.
// 8 stages x 8 channels (score: 32..63, output: 0..31), double-buffered LDS.
//
// ROUND 12: packed-f16 output accumulation, IN-PLACE weight storage.
// r11 FAILED (NaN): the separate w2[4][25] array added +100 live regs on top
// of s[4][25] at the t==3 conversion; under that pressure the allocator may
// spill/copy the asm-written pa/pb registers BETWEEN the volatile
// global_load_dwordx4 issue and the manual s_waitcnt vmcnt(0) -- reading a
// register whose load is still in flight => garbage/NaN. Session rule: with
// manually-waited asm loads, large liveness increases are a CORRECTNESS
// hazard. Fix: store the duplicated-f16 weight pair IN PLACE in s[p][k] via
// value-level __builtin_bit_cast (f32 scores before t==3, packed f16 bits
// after). Zero new registers; pressure profile identical to the r10 baseline
// that passed 7 rounds.
// Output stages: v_pk_fma_f16, one packed FMA per tap covers both channels
// (alo=.x, ahi=.y), ROW-CHUNKED: fresh f16 acc per window row (5-tap chains,
// +<=~0.008 err; test threshold is 0.08125, f32 baseline absmax 0.03125),
// merged to f32 per row. Inner output math ~400 -> ~280 instr/thread-stage.
// Keeps r4's volatile-asm pinned prefetch + manual vmcnt(0) drain verbatim.
__global__ __launch_bounds__(NTHR, 2)
void local_attn_kernel(const float* __restrict__ x,
                       const float* __restrict__ kern,
                       float* __restrict__ out)
{
    __shared__ unsigned ldsu[2 * 4 * PTILE];
    __shared__ float kw[K2];

    const int tid = threadIdx.x;
    for (int i = tid; i < 2 * 4 * PTILE; i += NTHR) ldsu[i] = 0u;
    if (tid < K2) kw[tid] = kern[tid] * (1.0f / KS);

    const int lane = tid & 63;
    const int wv   = tid >> 6;
    const int ty   = wv >> 1;                       // output row in block
    const int cg   = lane >> 5;                     // pair-half (0/1)
    const int tx   = ((wv & 1) << 5) | (lane & 31); // pixel-group 0..63
    const int w0   = tx << 2;

    // XCD swizzle: each XCD owns a contiguous 32-row band (halo L2-shared)
    const int bx     = blockIdx.x;
    const int hgroup = ((bx & 7) << 4) | (bx >> 3);
    const int h0     = hgroup * 2;
    const int h      = h0 + ty;
    const int b      = blockIdx.y;

    const float* xb = x + (size_t)b * 64 * PLANE;

    // 6 staging tasks/thread: task i -> (pair, tile row, 4-px segment)
    int gofs[6], lofs[6], pofs[6];
#pragma unroll
    for (int i = 0; i < 6; ++i) {
        const int rp   = (tid >> 6) + 4 * i;        // 0..23 (wave-uniform)
        const int row  = rp % 6;
        const int pair = rp / 6;
        const int r    = h0 - 2 + row;
        const bool v   = (unsigned)r < (unsigned)HH;
        gofs[i] = min(max(r, 0), HH - 1) * WW + (tid & 63) * 4;
        pofs[i] = pair * 2 * PLANE;
        lofs[i] = pair * PTILE + (v ? row : 6) * LROWD + 2 + (tid & 63) * 4;
    }

    f32x4 pa[6], pb[6];
    auto prefetch = [&](int st) {
        const float* xc = xb + (size_t)((st < 4) ? 32 + st * 8 : (st - 4) * 8) * PLANE;
#pragma unroll
        for (int i = 0; i < 6; ++i) {
            const float* p0 = xc + pofs[i] + gofs[i];
            const float* p1 = p0 + PLANE;
            // volatile asm: unsinkable, pinned at stage top in program order
            asm volatile("global_load_dwordx4 %0, %1, off"
                         : "=v"(pa[i]) : "v"(p0));
            asm volatile("global_load_dwordx4 %0, %1, off"
                         : "=v"(pb[i]) : "v"(p1));
        }
        __builtin_amdgcn_sched_barrier(0);
    };
    auto cvtwrite = [&](int bufi) {
        // compiler can't track the asm loads' vmcnt -- wait manually, and
        // fence the scheduler so pkrtz/ds_write can't hoist above the wait.
        asm volatile("s_waitcnt vmcnt(0)" ::: "memory");
        __builtin_amdgcn_sched_barrier(0);
        unsigned* lb = ldsu + bufi * 4 * PTILE;
#pragma unroll
        for (int i = 0; i < 6; ++i) {
            const unsigned d0 = pkrtz(pa[i].x, pb[i].x);
            const unsigned d1 = pkrtz(pa[i].y, pb[i].y);
            const unsigned d2 = pkrtz(pa[i].z, pb[i].z);
            const unsigned d3 = pkrtz(pa[i].w, pb[i].w);
            *(uint2*)(lb + lofs[i])     = make_uint2(d0, d1);
            *(uint2*)(lb + lofs[i] + 2) = make_uint2(d2, d3);
        }
    };

    // s[p][k]: f32 score accumulator until t==3 softmax; afterwards holds the
    // duplicated-f16 softmax weight pair (bit-cast in place, no extra regs).
    float s[4][K2];
#pragma unroll
    for (int p = 0; p < 4; ++p)
#pragma unroll
        for (int k = 0; k < K2; ++k) s[p][k] = 0.0f;

    __syncthreads();          // zero-init + kw visible
    prefetch(0);
    cvtwrite(0);
    __syncthreads();

#pragma unroll 1
    for (int t = 0; t < 8; ++t) {
        if (t + 1 < 8) prefetch(t + 1);
        const unsigned* buf = ldsu + (t & 1) * 4 * PTILE;

        if (t < 4) {
            // ---- score: 2 channel-pairs per lane-half, dot2 accumulate ----
#pragma unroll
            for (int dp = 0; dp < 2; ++dp) {
                const unsigned* tb = buf + (cg * 2 + dp) * PTILE;
                half2_t ctr[4];
                {   // center row (i=2) first: f[q] = pair at px w0-2+q
                    const unsigned* rp = tb + (ty + 2) * LROWD + w0;
                    const uint4 r0 = *(const uint4*)(rp);
                    const uint4 r1 = *(const uint4*)(rp + 4);
                    half2_t f[8] = {u2h(r0.x), u2h(r0.y), u2h(r0.z), u2h(r0.w),
                                    u2h(r1.x), u2h(r1.y), u2h(r1.z), u2h(r1.w)};
#pragma unroll
                    for (int p = 0; p < 4; ++p) ctr[p] = f[p + 2];
#pragma unroll
                    for (int j = 0; j < KS; ++j)
#pragma unroll
                        for (int p = 0; p < 4; ++p)
                            s[p][2 * KS + j] = dot2(f[p + j], ctr[p], s[p][2 * KS + j]);
                }
#pragma unroll
                for (int i = 0; i < KS; ++i) {
                    if (i == 2) continue;
                    const unsigned* rp = tb + (ty + i) * LROWD + w0;
                    const uint4 r0 = *(const uint4*)(rp);
                    const uint4 r1 = *(const uint4*)(rp + 4);
                    half2_t f[8] = {u2h(r0.x), u2h(r0.y), u2h(r0.z), u2h(r0.w),
                                    u2h(r1.x), u2h(r1.y), u2h(r1.z), u2h(r1.w)};
#pragma unroll
                    for (int j = 0; j < KS; ++j)
#pragma unroll
                        for (int p = 0; p < 4; ++p)
                            s[p][i * KS + j] = dot2(f[p + j], ctr[p], s[p][i * KS + j]);
                }
            }
            if (t == 3) {
                // combine pair-halves, then softmax over 25 taps.
                // zero-padded taps score exactly 0 and keep their denominator
                // share (matches reference). Each weight leaves this block as
                // a duplicated f16 pair stored IN PLACE in s[p][k].
#pragma unroll
                for (int p = 0; p < 4; ++p)
#pragma unroll
                    for (int k = 0; k < K2; ++k)
                        s[p][k] += __shfl_xor(s[p][k], 32, 64);
#pragma unroll
                for (int p = 0; p < 4; ++p) {
                    float mx = -INFINITY;
#pragma unroll
                    for (int k = 0; k < K2; ++k) {
                        float v = s[p][k] * kw[k];
                        s[p][k] = v;
                        mx = fmaxf(mx, v);
                    }
                    float sum = 0.0f;
#pragma unroll
                    for (int k = 0; k < K2; ++k) {
                        float e = __expf(s[p][k] - mx);
                        s[p][k] = e;
                        sum += e;
                    }
                    const float inv = 1.0f / sum;
#pragma unroll
                    for (int k = 0; k < K2; ++k) {
                        const float w = s[p][k] * inv;
                        s[p][k] = __builtin_bit_cast(float, pkrtz(w, w));
                    }
                }
            }
        } else {
            // ---- output: packed-f16 row-chunk accumulate, f32 merge ----
            const int chb = (t - 4) * 8;
#pragma unroll
            for (int dp = 0; dp < 2; ++dp) {
                const unsigned* tb = buf + (cg * 2 + dp) * PTILE;
                float alo[4] = {0.f, 0.f, 0.f, 0.f};
                float ahi[4] = {0.f, 0.f, 0.f, 0.f};
#pragma unroll
                for (int i = 0; i < KS; ++i) {
                    const unsigned* rp = tb + (ty + i) * LROWD + w0;
                    const uint4 r0 = *(const uint4*)(rp);
                    const uint4 r1 = *(const uint4*)(rp + 4);
                    half2_t f[8] = {u2h(r0.x), u2h(r0.y), u2h(r0.z), u2h(r0.w),
                                    u2h(r1.x), u2h(r1.y), u2h(r1.z), u2h(r1.w)};
                    // fresh f16 accumulator per row: 5-tap chains only
                    half2_t a2[4];
#pragma unroll
                    for (int p = 0; p < 4; ++p) a2[p] = half2_t{(_Float16)0, (_Float16)0};
#pragma unroll
                    for (int j = 0; j < KS; ++j)
#pragma unroll
                        for (int p = 0; p < 4; ++p) {
                            const half2_t wgt =
                                u2h(__builtin_bit_cast(unsigned, s[p][i * KS + j]));
                            a2[p] = f[p + j] * wgt + a2[p];   // v_pk_fma_f16
                        }
                    // merge row chunk into f32 accumulators
#pragma unroll
                    for (int p = 0; p < 4; ++p) {
                        alo[p] += (float)a2[p].x;
                        ahi[p] += (float)a2[p].y;
                    }
                }
                const int c0 = chb + (cg * 2 + dp) * 2;
                float* op = out + ((size_t)b * 32 + c0) * PLANE + h * WW + w0;
                *(float4*)op           = make_float4(alo[0], alo[1], alo[2], alo[3]);
                *(float4*)(op + PLANE) = make_float4(ahi[0], ahi[1], ahi[2], ahi[3]);
            }
        }

        if (t + 1 < 8) {
            cvtwrite((t + 1) & 1);
            __syncthreads();
        }
    }
}

extern "C" void kernel_launch(void* const* d_in, const int* in_sizes, int n_in,
                              void* d_out, int out_size, void* d_ws, size_t ws_size,
                              hipStream_t stream) {
    const float* x    = (const float*)d_in[0];
    const float* kern = (const float*)d_in[1];
    float*       out  = (float*)d_out;

    dim3 grid(HH / 2, BB, 1);
    dim3 block(NTHR, 1, 1);
    hipLaunchKernelGGL(local_attn_kernel, grid, block, 0, stream, x, kern, out);
}